// Round 1
// baseline (662.805 us; speedup 1.0000x reference)
//
#include <hip/hip_runtime.h>
#include <math.h>

#define BATCH 16384
#define IND   362
#define KP    384      // per-feature K padded to 384 (12 x 32)
#define HID   256
#define STY   60
#define NOUT  49710
#define OUTP  49920    // padded o-stride for Hrows (= 24 * 2080), zero-padded
#define D2    724
#define D2P   768

// ---- k_prep block ranges (256 threads each) ----
#define NB_SS   120                       // style_scalar
#define NB_HR   3120                      // Hrows convert: 2*64*49920/(256*8)
#define NB_CW   768                       // conv_w: 2*256*384/256
#define NB_CPN  384                       // conv_pnT
#define NB_CF   9216                      // conv_feat: 3*16384*48/256
#define NB_PREP (NB_SS + NB_HR + NB_CW + NB_CPN + NB_CF)

// ---- k_main block ranges ----
#define NB_HH   16                        // HH^T: 2 mats x 8 k-chunks
#define NB_PPB  2                         // P^T P: 2 mats
#define NB_HEAD (NB_HH + NB_PPB)
#define N_DT    46                        // d-tiles of 16 (46*16 = 736 >= 724)
#define N_OC    24                        // o-chunks of 2080 (24*2080 = 49920)
#define OCHUNK  2080
#define NB_M    (2 * N_DT * N_OC)         // 2208
#define NB_EMB  1024                      // 256 row-blocks x 4 col-blocks of 64
#define NB_SA   512
#define NB_MAIN (NB_HEAD + NB_M + NB_EMB + NB_SA)

typedef __bf16 bf16x8 __attribute__((ext_vector_type(8)));
typedef float  floatx4 __attribute__((ext_vector_type(4)));
typedef float  floatx2 __attribute__((ext_vector_type(2)));

__device__ inline floatx4 mfma16(bf16x8 a, bf16x8 b, floatx4 c) {
  return __builtin_amdgcn_mfma_f32_16x16x32_bf16(a, b, c, 0, 0, 0);
}

__device__ inline unsigned short f32_to_bf16(float x) {
  unsigned int u = __float_as_uint(x);
  unsigned int r = (u + 0x7FFFu + ((u >> 16) & 1u)) >> 16;
  return (unsigned short)r;
}

__device__ inline float sigm_fast(float x) { return 1.0f / (1.0f + __expf(-x)); }
__device__ inline float softplusf(float z) { return fmaxf(z, 0.0f) + log1pf(expf(-fabsf(z))); }

// =================== PHASE A: prep (converts + style scalars) ===================
__global__ __launch_bounds__(256) void k_prep(
    const float* __restrict__ fi, const float* __restrict__ fj, const float* __restrict__ fk,
    const float* __restrict__ Wt, const float* __restrict__ btop,
    const float* __restrict__ Wb, const float* __restrict__ bbot,
    const float* __restrict__ Pn, const float* __restrict__ Nn,
    const float* __restrict__ H1, const float* __restrict__ H2,
    unsigned short* __restrict__ fbf, unsigned short* __restrict__ wbfT,
    unsigned short* __restrict__ pnbfT, unsigned short* __restrict__ hrows,
    float* __restrict__ ss, float* __restrict__ cn) {
  __shared__ float sel[D2];
  __shared__ float shr[4];
  int b = blockIdx.x;
  int t = threadIdx.x;

  if (b < NB_SS) {
    // ---- per-style scalar scores + column norms (fp32 exact) ----
    int s  = b % STY;
    int mt = b / STY;
    const float* M = mt ? Nn : Pn;
    float cnp = 0.0f;
    for (int d = t; d < D2; d += 256) {
      float v = fmaxf(M[(size_t)d * STY + s], 0.0f);
      sel[d] = v;
      cnp += v * v;
    }
    __syncthreads();
    float at = btop[t], ab = bbot[t];
    for (int d = 0; d < IND; d++) at = fmaf(sel[d],       Wt[(size_t)d * HID + t], at);
    for (int d = 0; d < IND; d++) ab = fmaf(sel[IND + d], Wb[(size_t)d * HID + t], ab);
    float prod = (1.0f / (1.0f + expf(-at))) * (1.0f / (1.0f + expf(-ab)));
    for (int off = 32; off > 0; off >>= 1) prod += __shfl_xor(prod, off);
    if ((t & 63) == 0) shr[t >> 6] = prod;
    __syncthreads();
    if (t == 0) ss[mt * 64 + s] = shr[0] + shr[1] + shr[2] + shr[3];
    __syncthreads();
    for (int off = 32; off > 0; off >>= 1) cnp += __shfl_xor(cnp, off);
    if ((t & 63) == 0) shr[t >> 6] = cnp;
    __syncthreads();
    if (t == 0) cn[mt * 64 + s] = shr[0] + shr[1] + shr[2] + shr[3];
    return;
  }
  b -= NB_SS;

  if (b < NB_HR) {
    // ---- H1/H2 relu -> hrows [2][64][49920] bf16 row-major, zero-padded ----
    int e = (b * 256 + t) * 8;
    int row = e / OUTP;
    int o = e - row * OUTP;
    int s = row & 63;
    int mm = row >> 6;
    const float* H = mm ? H2 : H1;
    unsigned short* dst = hrows + (size_t)row * OUTP + o;
    unsigned int wv[4];
    if (s < STY && o + 8 <= NOUT) {
      const float* src = H + (size_t)s * NOUT + o;
      #pragma unroll
      for (int ee = 0; ee < 4; ee++) {
        floatx2 v = *(const floatx2*)(src + 2 * ee);
        wv[ee] = (unsigned)f32_to_bf16(fmaxf(v[0], 0.0f)) |
                 ((unsigned)f32_to_bf16(fmaxf(v[1], 0.0f)) << 16);
      }
    } else {
      #pragma unroll
      for (int ee = 0; ee < 4; ee++) {
        float lo = (s < STY && o + 2 * ee     < NOUT) ? fmaxf(H[(size_t)s * NOUT + o + 2 * ee],     0.0f) : 0.0f;
        float hi = (s < STY && o + 2 * ee + 1 < NOUT) ? fmaxf(H[(size_t)s * NOUT + o + 2 * ee + 1], 0.0f) : 0.0f;
        wv[ee] = (unsigned)f32_to_bf16(lo) | ((unsigned)f32_to_bf16(hi) << 16);
      }
    }
    uint4 v; v.x = wv[0]; v.y = wv[1]; v.z = wv[2]; v.w = wv[3];
    *(uint4*)dst = v;
    return;
  }
  b -= NB_HR;

  if (b < NB_CW) {
    // ---- W -> wbfT [2][256][384] (flat) ----
    int idx = b * 256 + t;
    int k = idx % KP;
    int rem = idx / KP;
    int h = rem % HID;
    int mm = rem / HID;
    const float* W = mm ? Wb : Wt;
    wbfT[idx] = f32_to_bf16(k < IND ? W[(size_t)k * HID + h] : 0.0f);
    return;
  }
  b -= NB_CW;

  if (b < NB_CPN) {
    // ---- P/N relu -> pnbfT [2][64][768] (feature-concat k layout, zero-padded) ----
    int u = b * 256 + t;
    int s = u & 63;
    int v = u >> 6;           // 0..1535
    int m = (v >= D2P) ? 1 : 0;
    int d = v - m * D2P;
    const float* M = m ? Nn : Pn;
    float x = (d < D2 && s < STY) ? fmaxf(M[(size_t)d * STY + s], 0.0f) : 0.0f;
    unsigned short bb = f32_to_bf16(x);
    int k = (d < IND) ? d : (d < D2 ? d + 22 : (d < 746 ? d - IND : d));
    pnbfT[((size_t)m * 64 + s) * D2P + k] = bb;
    return;
  }
  b -= NB_CPN;

  {
    // ---- features -> fbf bf16 (uint4 stores) ----
    long u = (long)b * 256 + t;
    int g = (int)(u % 48);
    long rf = u / 48;
    int row = (int)(rf % BATCH);
    int f = (int)(rf / BATCH);
    const float* src = (f == 0) ? fi : (f == 1 ? fj : fk);
    int d0 = g * 8;
    const float* sp = src + (size_t)row * IND + d0;
    unsigned int wv[4];
    #pragma unroll
    for (int e = 0; e < 4; e++) {
      int dd = d0 + 2 * e;
      float lo = (dd < IND)     ? sp[2 * e]     : 0.0f;
      float hi = (dd + 1 < IND) ? sp[2 * e + 1] : 0.0f;
      wv[e] = (unsigned)f32_to_bf16(lo) | ((unsigned)f32_to_bf16(hi) << 16);
    }
    uint4 v; v.x = wv[0]; v.y = wv[1]; v.z = wv[2]; v.w = wv[3];
    *(uint4*)(fbf + ((size_t)f * BATCH + row) * KP + d0) = v;
  }
}

// =================== PHASE B: main (MH^T-stream + HH^T/P^TP + emb + style_assign) ===================
__global__ __launch_bounds__(256, 4) void k_main(
    const unsigned short* __restrict__ fbf, const unsigned short* __restrict__ wbfT,
    const unsigned short* __restrict__ pnbfT, const unsigned short* __restrict__ hrows,
    const float* __restrict__ btop, const float* __restrict__ bbot,
    const float* __restrict__ cn, const float* __restrict__ ss,
    const float* __restrict__ mp, const float* __restrict__ mneg,
    const float* __restrict__ Pn, const float* __restrict__ Nn,
    float* __restrict__ sIJ, float* __restrict__ sIK,
    float* __restrict__ stIJ, float* __restrict__ stIK,
    float* __restrict__ HHb, float* __restrict__ PPb,
    float* __restrict__ partial) {
  __shared__ float shp[4];
  __shared__ float red[4096];
  int w = threadIdx.x >> 6, lane = threadIdx.x & 63;
  int m = lane & 15, q = lane >> 4;
  int b = blockIdx.x;

  if (b < NB_HEAD) {
    // ---------- HH^T (16 blocks) and P^T P (2 blocks): 64x64 gram matrices ----------
    bool isPP = (b >= NB_HH);
    int mat, chunk, nsteps, stride;
    const unsigned short* Rb;
    if (!isPP) { mat = b >> 3; chunk = b & 7; Rb = hrows + (size_t)mat * 64 * OUTP; stride = OUTP; nsteps = 195; }
    else       { mat = b - NB_HH; chunk = 0; Rb = pnbfT + (size_t)mat * 64 * D2P;  stride = D2P;  nsteps = 24;  }
    const unsigned short* Rm = Rb + (size_t)m * stride;

    floatx4 acc[4][4];
    #pragma unroll
    for (int a2 = 0; a2 < 4; a2++)
      #pragma unroll
      for (int b2 = 0; b2 < 4; b2++) acc[a2][b2] = (floatx4){0.f, 0.f, 0.f, 0.f};

    bf16x8 hc[4], hn[4];
    auto LD = [&](int j, bf16x8* h) {
      int k = (chunk * nsteps + j) * 32 + q * 8;
      #pragma unroll
      for (int st = 0; st < 4; st++)
        h[st] = *(const bf16x8*)(Rm + (size_t)(st * 16) * stride + k);
    };
    int j = w;
    LD(j, hc);
    for (; j < nsteps; j += 4) {
      if (j + 4 < nsteps) LD(j + 4, hn);
      #pragma unroll
      for (int a2 = 0; a2 < 4; a2++)
        #pragma unroll
        for (int b2 = 0; b2 < 4; b2++)
          acc[a2][b2] = mfma16(hc[a2], hc[b2], acc[a2][b2]);
      #pragma unroll
      for (int st = 0; st < 4; st++) hc[st] = hn[st];
    }
    for (int idx = threadIdx.x; idx < 4096; idx += 256) red[idx] = 0.f;
    __syncthreads();
    #pragma unroll
    for (int a2 = 0; a2 < 4; a2++)
      #pragma unroll
      for (int b2 = 0; b2 < 4; b2++)
        #pragma unroll
        for (int r = 0; r < 4; r++)
          atomicAdd(&red[(a2 * 16 + q * 4 + r) * 64 + b2 * 16 + m], acc[a2][b2][r]);
    __syncthreads();
    float* dst = (isPP ? PPb : HHb) + (size_t)mat * 4096;
    for (int idx = threadIdx.x; idx < 4096; idx += 256) atomicAdd(&dst[idx], red[idx]);
    return;
  }
  b -= NB_HEAD;

  if (b < NB_M) {
    // ---------- fused M-stream: Sum(M^2) - 2 * Sum(P .* (M H^T)) over this (d-tile, o-chunk) ----------
    int dt  = b % N_DT;
    int r   = b / N_DT;
    int oc  = r % N_OC;
    int mat = r / N_OC;
    int d0 = dt * 16, o0 = oc * OCHUNK;
    bool full = (o0 + OCHUNK <= NOUT);
    int d = d0 + m;
    bool rowok = (d < D2);
    const float* Mrow = (mat ? mneg : mp) + (size_t)d * NOUT;
    const unsigned short* Hbase = hrows + ((size_t)mat * 64 + m) * OUTP;

    floatx4 acc[4];
    #pragma unroll
    for (int st = 0; st < 4; st++) acc[st] = (floatx4){0.f, 0.f, 0.f, 0.f};
    float msq = 0.0f;

    floatx2 mc[4], mnx[4];
    bf16x8  hc[4], hn[4];

    auto LOADM = [&](int j, floatx2* dst) {
      int o = o0 + j * 32 + q * 8;
      if (rowok) {
        const float* Mr = Mrow + o;
        if (full) {
          dst[0] = *(const floatx2*)(Mr);
          dst[1] = *(const floatx2*)(Mr + 2);
          dst[2] = *(const floatx2*)(Mr + 4);
          dst[3] = *(const floatx2*)(Mr + 6);
        } else {
          #pragma unroll
          for (int e = 0; e < 4; e++) {
            floatx2 v = {0.f, 0.f};
            if (o + 2 * e     < NOUT) v[0] = Mr[2 * e];
            if (o + 2 * e + 1 < NOUT) v[1] = Mr[2 * e + 1];
            dst[e] = v;
          }
        }
      } else {
        #pragma unroll
        for (int e = 0; e < 4; e++) dst[e] = (floatx2){0.f, 0.f};
      }
    };
    auto LOADH = [&](int j, bf16x8* h) {
      int o = o0 + j * 32 + q * 8;
      #pragma unroll
      for (int st = 0; st < 4; st++)
        h[st] = *(const bf16x8*)(Hbase + (size_t)(st * 16) * OUTP + o);
    };

    LOADM(w, mc);
    LOADH(w, hc);
    for (int j = w; j < 65; j += 4) {
      if (j + 4 < 65) { LOADM(j + 4, mnx); LOADH(j + 4, hn); }
      // convert current M to bf16 fragment + accumulate M^2 in fp32
      union { unsigned int u32[4]; bf16x8 v; } cv;
      #pragma unroll
      for (int e = 0; e < 4; e++) {
        msq = fmaf(mc[e][0], mc[e][0], msq);
        msq = fmaf(mc[e][1], mc[e][1], msq);
        cv.u32[e] = (unsigned)f32_to_bf16(mc[e][0]) | ((unsigned)f32_to_bf16(mc[e][1]) << 16);
      }
      bf16x8 af = cv.v;
      #pragma unroll
      for (int st = 0; st < 4; st++) acc[st] = mfma16(af, hc[st], acc[st]);
      #pragma unroll
      for (int e = 0; e < 4; e++) mc[e] = mnx[e];
      #pragma unroll
      for (int st = 0; st < 4; st++) hc[st] = hn[st];
    }

    // epilogue: fold -2 * P .* acc into scalar (P in fp32 from original inputs)
    const float* PM = mat ? Nn : Pn;
    float t2 = 0.0f;
    #pragma unroll
    for (int st = 0; st < 4; st++) {
      int s = st * 16 + m;
      if (s < STY) {
        #pragma unroll
        for (int rg = 0; rg < 4; rg++) {
          int dd = d0 + q * 4 + rg;
          if (dd < D2) {
            float pv = fmaxf(PM[(size_t)dd * STY + s], 0.0f);
            t2 = fmaf(pv, acc[st][rg], t2);
          }
        }
      }
    }
    float local = msq - 2.0f * t2;
    for (int off = 32; off > 0; off >>= 1) local += __shfl_xor(local, off);
    if (lane == 0) shp[w] = local;
    __syncthreads();
    if (threadIdx.x == 0) partial[b] = shp[0] + shp[1] + shp[2] + shp[3];
    return;
  }
  b -= NB_M;

  if (b < NB_EMB) {
    // ---------- embedding GEMMs + ij/ik scores (64 rows x 64 hidden cols per block) ----------
    int r0 = (b & 255) * 64 + w * 16;
    int hb = (b >> 8) * 64;
    const unsigned short* fi = fbf + (size_t)(r0 + m) * KP + q * 8;
    const unsigned short* fj = fi + (size_t)BATCH * KP;
    const unsigned short* fk = fj + (size_t)BATCH * KP;
    floatx4 accI[4], accJ[4], accK[4];
    #pragma unroll
    for (int nt = 0; nt < 4; nt++) {
      accI[nt] = (floatx4){0.f, 0.f, 0.f, 0.f};
      accJ[nt] = (floatx4){0.f, 0.f, 0.f, 0.f};
      accK[nt] = (floatx4){0.f, 0.f, 0.f, 0.f};
    }
    for (int kc = 0; kc < 12; kc++) {
      bf16x8 ai = *(const bf16x8*)(fi + kc * 32);
      bf16x8 aj = *(const bf16x8*)(fj + kc * 32);
      bf16x8 ak = *(const bf16x8*)(fk + kc * 32);
      #pragma unroll
      for (int nt = 0; nt < 4; nt++) {
        int n = hb + nt * 16 + m;
        const unsigned short* wp = wbfT + (size_t)n * KP + kc * 32 + q * 8;
        bf16x8 bt8 = *(const bf16x8*)(wp);
        bf16x8 bb8 = *(const bf16x8*)(wp + (size_t)HID * KP);
        accI[nt] = mfma16(ai, bt8, accI[nt]);
        accJ[nt] = mfma16(aj, bb8, accJ[nt]);
        accK[nt] = mfma16(ak, bb8, accK[nt]);
      }
    }
    float sij[4] = {0.f, 0.f, 0.f, 0.f}, sik[4] = {0.f, 0.f, 0.f, 0.f};
    #pragma unroll
    for (int nt = 0; nt < 4; nt++) {
      int n = hb + nt * 16 + m;
      float vbt = btop[n], vbb = bbot[n];
      #pragma unroll
      for (int reg = 0; reg < 4; reg++) {
        float ti = sigm_fast(accI[nt][reg] + vbt);
        float tj = sigm_fast(accJ[nt][reg] + vbb);
        float tk = sigm_fast(accK[nt][reg] + vbb);
        sij[reg] += ti * tj;
        sik[reg] += ti * tk;
      }
    }
    #pragma unroll
    for (int reg = 0; reg < 4; reg++) {
      for (int off = 1; off < 16; off <<= 1) {
        sij[reg] += __shfl_xor(sij[reg], off);
        sik[reg] += __shfl_xor(sik[reg], off);
      }
    }
    if (m == 0) {
      #pragma unroll
      for (int reg = 0; reg < 4; reg++) {
        int row = r0 + q * 4 + reg;
        atomicAdd(&sIJ[row], sij[reg]);
        atomicAdd(&sIK[row], sik[reg]);
      }
    }
    return;
  }
  b -= NB_EMB;

  {
    // ---------- style argmin + gather ----------
    int mat = w & 1;
    int r0 = b * 32 + (w >> 1) * 16;
    const unsigned short* fA = fbf + (size_t)(r0 + m) * KP + q * 8;
    const unsigned short* fB = fA + (size_t)(1 + mat) * BATCH * KP;
    const unsigned short* Bp = pnbfT + (size_t)mat * 64 * D2P + q * 8;
    floatx4 acc[4];
    #pragma unroll
    for (int nt = 0; nt < 4; nt++) acc[nt] = (floatx4){0.f, 0.f, 0.f, 0.f};
    for (int kc = 0; kc < 24; kc++) {
      bf16x8 a = (kc < 12) ? *(const bf16x8*)(fA + kc * 32)
                           : *(const bf16x8*)(fB + (kc - 12) * 32);
      #pragma unroll
      for (int nt = 0; nt < 4; nt++) {
        bf16x8 bb = *(const bf16x8*)(Bp + (size_t)(nt * 16 + m) * D2P + kc * 32);
        acc[nt] = mfma16(a, bb, acc[nt]);
      }
    }
    const float* cnm = cn + mat * 64;
    float bv[4]; int bi[4];
    #pragma unroll
    for (int reg = 0; reg < 4; reg++) { bv[reg] = __builtin_inff(); bi[reg] = 1 << 30; }
    #pragma unroll
    for (int nt = 0; nt < 4; nt++) {
      int s = nt * 16 + m;
      float c = cnm[s & 63];
      #pragma unroll
      for (int reg = 0; reg < 4; reg++) {
        float d2 = (s < STY) ? (c - 2.0f * acc[nt][reg]) : __builtin_inff();
        if (d2 < bv[reg] || (d2 == bv[reg] && s < bi[reg])) { bv[reg] = d2; bi[reg] = s; }
      }
    }
    for (int off = 1; off < 16; off <<= 1) {
      #pragma unroll
      for (int reg = 0; reg < 4; reg++) {
        float ov = __shfl_xor(bv[reg], off);
        int   oi = __shfl_xor(bi[reg], off);
        if (ov < bv[reg] || (ov == bv[reg] && oi < bi[reg])) { bv[reg] = ov; bi[reg] = oi; }
      }
    }
    if (m == 0) {
      float* dst = mat ? stIK : stIJ;
      const float* ssm = ss + mat * 64;
      #pragma unroll
      for (int reg = 0; reg < 4; reg++) dst[r0 + q * 4 + reg] = ssm[bi[reg]];
    }
  }
}

// =================== PHASE C: final reductions ===================
__global__ __launch_bounds__(256) void k_final(
    const float* __restrict__ sIJ, const float* __restrict__ sIK,
    const float* __restrict__ stIJ, const float* __restrict__ stIK,
    const float* __restrict__ l3partial,
    const float* __restrict__ HHb, const float* __restrict__ PPb,
    float* __restrict__ out) {
  int t = threadIdx.x;
  float l1 = 0.f, l2 = 0.f, ac = 0.f;
  for (int r = t; r < BATCH; r += 256) {
    float dij = sIJ[r] - sIK[r];
    l1 += softplusf(-dij);
    if (dij >= 0.0f) ac += 1.0f;
    float dst = stIJ[r] - stIK[r];
    l2 += softplusf(-dst);
  }
  double l3 = 0.0;
  for (int p = t; p < NB_M; p += 256) l3 += (double)l3partial[p];
  for (int idx = t; idx < 8192; idx += 256) l3 += (double)HHb[idx] * (double)PPb[idx];
  __shared__ float sh1[4], sh2[4], sh3[4];
  __shared__ double sh4[4];
  for (int off = 32; off > 0; off >>= 1) {
    l1 += __shfl_xor(l1, off);
    l2 += __shfl_xor(l2, off);
    ac += __shfl_xor(ac, off);
    l3 += __shfl_xor(l3, off);
  }
  if ((t & 63) == 0) { sh1[t >> 6] = l1; sh2[t >> 6] = l2; sh3[t >> 6] = ac; sh4[t >> 6] = l3; }
  __syncthreads();
  if (t == 0) {
    double L1 = 0, L2 = 0, AC = 0, L3 = 0;
    for (int i = 0; i < 4; i++) { L1 += sh1[i]; L2 += sh2[i]; AC += sh3[i]; L3 += sh4[i]; }
    L1 /= BATCH; L2 /= BATCH; AC /= BATCH;
    L3 /= ((double)D2 * (double)NOUT);
    out[0] = (float)(L1 + L2 + 0.1 * L3);
    out[1] = (float)L1;
    out[2] = (float)L2;
    out[3] = (float)L3;
    out[4] = (float)AC;
  }
}

extern "C" void kernel_launch(void* const* d_in, const int* in_sizes, int n_in,
                              void* d_out, int out_size, void* d_ws, size_t ws_size,
                              hipStream_t stream) {
  (void)in_sizes; (void)n_in; (void)out_size; (void)ws_size;
  const float* i_f  = (const float*)d_in[0];
  const float* j_f  = (const float*)d_in[1];
  const float* k_f  = (const float*)d_in[2];
  const float* W_t  = (const float*)d_in[3];
  const float* b_t  = (const float*)d_in[4];
  const float* W_b  = (const float*)d_in[5];
  const float* b_b  = (const float*)d_in[6];
  const float* P_n  = (const float*)d_in[7];
  const float* N_n  = (const float*)d_in[8];
  const float* H1   = (const float*)d_in[9];
  const float* H2   = (const float*)d_in[10];
  const float* Mp   = (const float*)d_in[11];
  const float* Mn   = (const float*)d_in[12];
  float* out = (float*)d_out;
  char* ws = (char*)d_ws;

  const size_t OFF_FBF   = 0;
  const size_t OFF_WBFT  = OFF_FBF   + (size_t)3 * BATCH * KP * 2;
  const size_t OFF_PNBFT = OFF_WBFT  + (size_t)2 * HID * KP * 2;
  const size_t OFF_HROWS = OFF_PNBFT + (size_t)2 * 64 * D2P * 2;
  const size_t OFF_SIJ   = OFF_HROWS + (size_t)2 * 64 * OUTP * 2;
  const size_t OFF_SIK   = OFF_SIJ   + (size_t)BATCH * 4;
  const size_t OFF_HH    = OFF_SIK   + (size_t)BATCH * 4;
  const size_t OFF_PP    = OFF_HH    + (size_t)2 * 4096 * 4;
  const size_t OFF_STIJ  = OFF_PP    + (size_t)2 * 4096 * 4;
  const size_t OFF_STIK  = OFF_STIJ  + (size_t)BATCH * 4;
  const size_t OFF_SS    = OFF_STIK  + (size_t)BATCH * 4;
  const size_t OFF_CN    = OFF_SS    + 512;
  const size_t OFF_L3P   = OFF_CN    + 512;

  unsigned short* fbf   = (unsigned short*)(ws + OFF_FBF);
  unsigned short* wbfT  = (unsigned short*)(ws + OFF_WBFT);
  unsigned short* pnbfT = (unsigned short*)(ws + OFF_PNBFT);
  unsigned short* hrows = (unsigned short*)(ws + OFF_HROWS);
  float*  sIJ  = (float*)(ws + OFF_SIJ);
  float*  sIK  = (float*)(ws + OFF_SIK);
  float*  HHb  = (float*)(ws + OFF_HH);
  float*  PPb  = (float*)(ws + OFF_PP);
  float*  stIJ = (float*)(ws + OFF_STIJ);
  float*  stIK = (float*)(ws + OFF_STIK);
  float*  ss   = (float*)(ws + OFF_SS);
  float*  cn   = (float*)(ws + OFF_CN);
  float*  l3p  = (float*)(ws + OFF_L3P);

  // zero: sIJ, sIK (atomic targets) + HH, PP (atomic targets) — contiguous
  hipMemsetAsync(ws + OFF_SIJ, 0, (size_t)BATCH * 4 * 2 + (size_t)4 * 4096 * 4, stream);

  k_prep<<<NB_PREP, 256, 0, stream>>>(i_f, j_f, k_f, W_t, b_t, W_b, b_b,
                                      P_n, N_n, H1, H2,
                                      fbf, wbfT, pnbfT, hrows, ss, cn);
  k_main<<<NB_MAIN, 256, 0, stream>>>(fbf, wbfT, pnbfT, hrows,
                                      b_t, b_b, cn, ss, Mp, Mn, P_n, N_n,
                                      sIJ, sIK, stIJ, stIK, HHb, PPb, l3p);
  k_final<<<1, 256, 0, stream>>>(sIJ, sIK, stIJ, stIK, l3p, HHb, PPb, out);
}